// Round 2
// baseline (118.384 us; speedup 1.0000x reference)
//
#include <hip/hip_runtime.h>
#include <hip/hip_bf16.h>

// CARAFE fused: B=4, C=128, H=W=64, C_MID=64, S=2, K=5
// Round 12: phase-E reassembly rewritten as MFMA GEMM.
//   out[(pix,g)][c] = sum_hp W[(pix,g)][hp] * X[hp][c], W = scattered softmax ker
//   (64x64, hi+lo bf16 split for precision), X = xsT[c][hp] swizzled LDS copy.
// Phase B A-frags now read from L2 (XG) directly; hs XOR-swizzled (stride 64).
// LDS 40,064 B -> 4 blocks/CU; 1024 blocks x 512 threads.
#define HW 4096

typedef __attribute__((ext_vector_type(8))) short  short8;   // 8 bf16 (4 VGPRs)
typedef __attribute__((ext_vector_type(4))) float  floatx4;  // MFMA C/D
typedef __attribute__((ext_vector_type(4))) unsigned short ushort4v;

// workspace (BYTE offsets)
#define OFF_W2B 0ul        // bf16 [112][576]  = 129024 B   w2b[n][k], k = tap*64 + c
#define OFF_W1B 129024ul   // bf16 [64][128]   = 16384 B    w1b[o][c]
#define OFF_BN  145408ul   // float2[64]       = 512 B      (inv, add) per o
#define OFF_XG  145920ul   // bf16 [4][16][4096][8] = 4 MB  x transposed: [b][cq][pix][8c]
#define OFF_XPP 4340224ul  // bf16 [4*128][68][68]  = 4.73 MB zero-padded planar x

// ---------------- prep ----------------
__global__ __launch_bounds__(256) void prep_kernel(const float* __restrict__ x,
                                                   const float* __restrict__ w1,
                                                   const float* __restrict__ w2,
                                                   const float* __restrict__ gamma,
                                                   const float* __restrict__ beta,
                                                   const float* __restrict__ mean,
                                                   const float* __restrict__ var,
                                                   char* __restrict__ ws) {
    int tid = blockIdx.x * 256 + threadIdx.x;
    if (tid < 262144) {
        int pix = tid & 4095;
        int cq  = (tid >> 12) & 15;
        int b   = tid >> 16;
        const float* xp = x + ((size_t)(b * 128 + cq * 8)) * HW + pix;
        union { short8 s; __hip_bfloat16 h[8]; } u;
        #pragma unroll
        for (int cc = 0; cc < 8; ++cc) u.h[cc] = __float2bfloat16(xp[(size_t)cc * HW]);
        *(short8*)((__hip_bfloat16*)(ws + OFF_XG) + (size_t)tid * 8) = u.s;
        return;
    }
    int t2 = tid - 262144;
    if (t2 < 64512) {
        int n = t2 / 576;
        int k = t2 - n * 576;        // k = tap*64 + c
        int t = k >> 6, c = k & 63;
        float v = (n < 100) ? w2[(n * 64 + c) * 9 + t] : 0.f;
        ((__hip_bfloat16*)(ws + OFF_W2B))[t2] = __float2bfloat16(v);
    } else if (t2 < 64512 + 8192) {
        int i = t2 - 64512;
        ((__hip_bfloat16*)(ws + OFF_W1B))[i] = __float2bfloat16(w1[i]);
    } else if (t2 < 64512 + 8192 + 64) {
        int o = t2 - 64512 - 8192;
        float inv = gamma[o] * rsqrtf(var[o] + 1e-5f);
        ((float2*)(ws + OFF_BN))[o] = make_float2(inv, beta[o] - mean[o] * inv);
    } else {
        int t3 = t2 - 72768;          // XPP: zero-padded planar bf16 copy
        if (t3 < 591872) {            // 512 bc * 68 rows * 17 chunks
            int j  = t3 % 17;
            int rr = t3 / 17;         // (b*128+c)*68 + row68
            int row68 = rr - (rr / 68) * 68;
            int bc = rr / 68;
            int gy = row68 - 2;
            const float* xp = x + (size_t)bc * HW + (size_t)gy * 64;
            union { ushort4v u4; __hip_bfloat16 h[4]; } u;
            #pragma unroll
            for (int e = 0; e < 4; ++e) {
                int gx = j * 4 + e - 2;
                float f = 0.f;
                if ((unsigned)gy < 64u && (unsigned)gx < 64u) f = xp[gx];
                u.h[e] = __float2bfloat16(f);
            }
            *(ushort4v*)((__hip_bfloat16*)(ws + OFF_XPP) + (size_t)rr * 68 + j * 4) = u.u4;
        }
    }
}

// ---------------- fused CARAFE: one block per (b, 4x4 tile), 512 threads = 8 waves ----------
// LDS (40,064 B):
//   xsT [128 c][64 hp] bf16 swz  @ 0      (16384)  live A..E
//   lg  [16 pix][114]  f32       @ 16384  ( 7296)  live C..D
//   hs  [36 pix][64 c] bf16 swz  @ 23680  ( 4608)  live B..C } aliased pool (16384)
//   Whi/Wlo [64][64]  bf16 swz   @ 23680  (16384)  live D..E }
__global__ __launch_bounds__(512, 8) void fused_carafe(const char* __restrict__ ws,
                                                       float* __restrict__ out) {
    __shared__ __align__(16) char smem[40064];
    __hip_bfloat16* xsT = (__hip_bfloat16*)smem;
    float*          lg  = (float*)(smem + 16384);
    __hip_bfloat16* hs  = (__hip_bfloat16*)(smem + 23680);
    __hip_bfloat16* Whi = (__hip_bfloat16*)(smem + 23680);   // Wlo = Whi + 4096 elems

    int b    = blockIdx.x >> 8;
    int tile = blockIdx.x & 255;
    int ty0 = (tile >> 4) * 4;
    int tx0 = (tile & 15) * 4;
    int tid = threadIdx.x;
    int lane = tid & 63, wave = tid >> 6;   // 8 waves
    int q = lane >> 4, m = lane & 15;

    // ---- phase A: stage xsT[c][hp] from padded planar XPP; chunk-XOR swizzle ----
    const __hip_bfloat16* xpp = (const __hip_bfloat16*)(ws + OFF_XPP);
    #pragma unroll
    for (int it = 0; it < 2; ++it) {
        int idx = tid + it * 512;             // 1024 = 128 c * 8 h-rows
        int c = idx >> 3, h = idx & 7;
        size_t rb = ((size_t)(b * 128 + c) * 68 + (ty0 + h)) * 68 + tx0;  // 8B aligned
        union { short8 s; uint2 d[2]; } u;
        u.d[0] = *(const uint2*)(xpp + rb);
        u.d[1] = *(const uint2*)(xpp + rb + 4);
        *(short8*)(xsT + c * 64 + ((h ^ (c & 7)) << 3)) = u.s;
    }

    // ---- phase B: h = relu(bn(w1 @ x)); M=36 halo pix (6x6), N=64, K=128 ----
    // A-frags straight from L2 (XG layout); 12 tasks (3 mt x 4 nt) over 8 waves
    {
        const __hip_bfloat16* xg  = (const __hip_bfloat16*)(ws + OFF_XG) + (size_t)b * 16 * 4096 * 8;
        const __hip_bfloat16* w1b = (const __hip_bfloat16*)(ws + OFF_W1B);
        for (int task = wave; task < 12; task += 8) {
            int mt = task >> 2, nt = task & 3;
            int bo = nt * 16 + m;
            float2 bnia = ((const float2*)(ws + OFF_BN))[bo];
            int hp = mt * 16 + m;
            int hpc = (hp < 36) ? hp : 0;          // clamp dead A-rows (C rows discarded)
            int hy1 = hpc / 6, hx1 = hpc - hy1 * 6;
            int gy = ty0 + hy1 - 1, gx = tx0 + hx1 - 1;
            int gyc = min(max(gy, 0), 63), gxc = min(max(gx, 0), 63);
            int pix = gyc * 64 + gxc;
            floatx4 acc;
            #pragma unroll
            for (int r = 0; r < 4; ++r) acc[r] = 0.f;
            #pragma unroll
            for (int s = 0; s < 4; ++s) {
                short8 a  = *(const short8*)(xg + ((size_t)((s * 4 + q) * 4096 + pix)) * 8);
                short8 bw = *(const short8*)(w1b + bo * 128 + s * 32 + q * 8);
                acc = __builtin_amdgcn_mfma_f32_16x16x32_bf16(a, bw, acc, 0, 0, 0);
            }
            #pragma unroll
            for (int r = 0; r < 4; ++r) {
                int prow = mt * 16 + q * 4 + r;
                if (prow < 36) {
                    int phy = prow / 6, phx = prow - phy * 6;
                    int gy2 = ty0 + phy - 1, gx2 = tx0 + phx - 1;
                    bool in = ((unsigned)gy2 < 64u) && ((unsigned)gx2 < 64u);
                    float v = in ? fmaxf(fmaf(acc[r], bnia.x, bnia.y), 0.f) : 0.f;
                    hs[prow * 64 + ((((bo >> 3) ^ (prow & 7)) << 3) | (bo & 7))] = __float2bfloat16(v);
                }
            }
        }
    }
    __syncthreads();

    // ---- phase C: 3x3 conv via MFMA: M=16 pix, N=112, K=576; 7 n-tile tasks ----
    if (wave < 7) {
        int nt = wave;
        int py = m >> 2, px = m & 3;
        const __hip_bfloat16* w2b = (const __hip_bfloat16*)(ws + OFF_W2B);
        const __hip_bfloat16* bp  = w2b + (size_t)(nt * 16 + m) * 576 + q * 8;

        floatx4 acc;
        #pragma unroll
        for (int r = 0; r < 4; ++r) acc[r] = 0.f;

        short8 bcur = *(const short8*)bp;
        for (int s = 0; s < 18; ++s) {
            int t = s >> 1, co = (s & 1) * 4 + q;      // c-oct index 0..7
            int ti = t / 3, tj = t - ti * 3;
            int row = (py + ti) * 6 + (px + tj);
            short8 a = *(const short8*)(hs + row * 64 + ((co ^ (row & 7)) << 3));
            short8 bn2 = bcur;
            if (s < 17) bn2 = *(const short8*)(bp + (s + 1) * 32);
            acc = __builtin_amdgcn_mfma_f32_16x16x32_bf16(a, bcur, acc, 0, 0, 0);
            bcur = bn2;
        }
        #pragma unroll
        for (int r = 0; r < 4; ++r)
            lg[(q * 4 + r) * 114 + nt * 16 + m] = acc[r];
    }
    __syncthreads();

    // ---- phase D1: zero Whi/Wlo (aliases hs, now dead) ----
    {
        short8 z;
        #pragma unroll
        for (int j = 0; j < 8; ++j) z[j] = 0;
        *(short8*)((char*)Whi + tid * 16) = z;          // 512*16 = 8192 = Whi
        *(short8*)((char*)Whi + 8192 + tid * 16) = z;   // Wlo
    }
    __syncthreads();

    // ---- phase D2: softmax over 25 taps -> scatter into W rows (hi + lo bf16) ----
    if (tid < 64) {
        int pixid = tid >> 2, g = tid & 3;              // row = pix*4 + g = tid
        int py = pixid >> 2, px = pixid & 3;
        float v[25];
        #pragma unroll
        for (int wi = 0; wi < 25; ++wi) v[wi] = lg[pixid * 114 + g * 25 + wi];
        float mx = v[0];
        #pragma unroll
        for (int wi = 1; wi < 25; ++wi) mx = fmaxf(mx, v[wi]);
        float ssum = 0.f;
        #pragma unroll
        for (int wi = 0; wi < 25; ++wi) { v[wi] = __expf(v[wi] - mx); ssum += v[wi]; }
        float rs = 1.f / ssum;
        int row = tid;
        #pragma unroll
        for (int t25 = 0; t25 < 25; ++t25) {
            int ti = t25 / 5, tj = t25 - ti * 5;
            int addr = row * 64 + ((((py + ti) ^ (row & 7)) << 3) | (px + tj));
            float kv = v[t25] * rs;
            __hip_bfloat16 khi = __float2bfloat16(kv);
            Whi[addr] = khi;
            Whi[4096 + addr] = __float2bfloat16(kv - __bfloat162float(khi));
        }
    }
    __syncthreads();

    // ---- phase E: reassembly as MFMA: out[64 pixg][128 c] = (Whi+Wlo)[64x64] @ X[64x128] ----
    // wave = nt (c-block); mt loop 0..3; K = 64 halo pix in 2 steps of 32.
    {
        int nt = wave;
        int c = nt * 16 + m;
        const __hip_bfloat16* xr = xsT + c * 64;
        short8 b0 = *(const short8*)(xr + ((q ^ (c & 7)) << 3));
        short8 b1 = *(const short8*)(xr + (((4 + q) ^ (c & 7)) << 3));
        float* outc = out + (((size_t)b * 128 + c) << 14);   // channel plane 128*128
        #pragma unroll
        for (int mt = 0; mt < 4; ++mt) {
            int row = mt * 16 + m;
            const __hip_bfloat16* wr = Whi + row * 64;
            int s0 = ((q ^ (row & 7)) << 3);
            int s1 = (((4 + q) ^ (row & 7)) << 3);
            short8 ah0 = *(const short8*)(wr + s0);
            short8 al0 = *(const short8*)(wr + 4096 + s0);
            short8 ah1 = *(const short8*)(wr + s1);
            short8 al1 = *(const short8*)(wr + 4096 + s1);
            floatx4 acc;
            #pragma unroll
            for (int r = 0; r < 4; ++r) acc[r] = 0.f;
            acc = __builtin_amdgcn_mfma_f32_16x16x32_bf16(ah0, b0, acc, 0, 0, 0);
            acc = __builtin_amdgcn_mfma_f32_16x16x32_bf16(al0, b0, acc, 0, 0, 0);
            acc = __builtin_amdgcn_mfma_f32_16x16x32_bf16(ah1, b1, acc, 0, 0, 0);
            acc = __builtin_amdgcn_mfma_f32_16x16x32_bf16(al1, b1, acc, 0, 0, 0);
            // D rows: pixg = mt*16 + q*4 + r -> pix = mt*4+q (py=mt, px=q), g = r
            float* op = outc + (size_t)(2 * (ty0 + mt)) * 128 + 2 * (tx0 + q);
            *(float2*)op         = make_float2(acc[0], acc[1]);   // gy=0: gx=0,1
            *(float2*)(op + 128) = make_float2(acc[2], acc[3]);   // gy=1: gx=0,1
        }
    }
}

extern "C" void kernel_launch(void* const* d_in, const int* in_sizes, int n_in,
                              void* d_out, int out_size, void* d_ws, size_t ws_size,
                              hipStream_t stream) {
    const float* x     = (const float*)d_in[0];
    const float* w1    = (const float*)d_in[1];
    const float* w2    = (const float*)d_in[2];
    const float* gamma = (const float*)d_in[3];
    const float* beta  = (const float*)d_in[4];
    const float* mean  = (const float*)d_in[5];
    const float* var   = (const float*)d_in[6];
    float* out = (float*)d_out;
    char*  ws  = (char*)d_ws;

    prep_kernel<<<3621, 256, 0, stream>>>(x, w1, w2, gamma, beta, mean, var, ws);
    fused_carafe<<<1024, 512, 0, stream>>>(ws, out);
}